// Round 1
// baseline (2163.580 us; speedup 1.0000x reference)
//
#include <hip/hip_runtime.h>
#include <cstddef>

// Model dims
#define WEMB 300
#define HID  256
#define SEN2 512
#define NB   64
#define NS   10
#define NL   30
#define NTL  15
#define NSEN 640           // B*S sentence sequences
#define NROWS_SEN 1408     // 640 fwd + 640 bwd + 64 head fwd + 64 head bwd

__device__ __forceinline__ float sigm(float x) { return 1.f / (1.f + expf(-x)); }

// ============================================================================
// proj_gemm: out[M,2048] = A[M,K] @ [Wf|Wb]^T + [bf|bb]
// A is either gathered embedding rows (ids0/ids1 split) or a dense matrix.
// BM=BN=128, BK=16, 256 threads, 8x8 per thread as 4+4 split tiles (2-way LDS
// bank aliasing only, which is free on gfx950).
// ============================================================================
__global__ __launch_bounds__(256) void proj_gemm(
    const float* __restrict__ A,
    const int* __restrict__ ids0, const int* __restrict__ ids1, int idsSplit,
    int M, int K,
    const float* __restrict__ Wf, const float* __restrict__ Wb,
    const float* __restrict__ bf, const float* __restrict__ bb,
    float* __restrict__ out)
{
    __shared__ float As[16][129];
    __shared__ float Bs[16][129];
    const int tid = threadIdx.x;
    const int bm = blockIdx.x * 128;
    const int bn = blockIdx.y * 128;
    const float* W    = (bn < 1024) ? Wf : Wb;
    const float* bias = (bn < 1024) ? bf : bb;
    const int wcol0   = (bn < 1024) ? bn : bn - 1024;

    // loaders: each thread loads 8 consecutive k for one row/col
    const int aRow = tid >> 1;
    const int aK0  = (tid & 1) * 8;
    int grow = bm + aRow;
    bool aValid = (grow < M);
    const float* aPtr;
    if (ids0) {
        int id = 0;
        if (grow < idsSplit) id = ids0[grow];
        else if (grow < M)   id = ids1[grow - idsSplit];
        aPtr = A + (size_t)id * K;
    } else {
        aPtr = A + (size_t)(aValid ? grow : 0) * K;
    }
    const float* wPtr = W + (size_t)(wcol0 + aRow) * K;  // col = aRow mapping

    const int tx = tid & 15, ty = tid >> 4;
    float acc[8][8];
#pragma unroll
    for (int i = 0; i < 8; i++)
#pragma unroll
        for (int j = 0; j < 8; j++) acc[i][j] = 0.f;

    for (int k0 = 0; k0 < K; k0 += 16) {
#pragma unroll
        for (int i = 0; i < 8; i++) {
            int k = k0 + aK0 + i;
            As[aK0 + i][aRow] = (aValid && k < K) ? aPtr[k] : 0.f;
            Bs[aK0 + i][aRow] = (k < K) ? wPtr[k] : 0.f;
        }
        __syncthreads();
#pragma unroll
        for (int kk = 0; kk < 16; kk++) {
            float a[8], b[8];
#pragma unroll
            for (int i = 0; i < 4; i++) {
                a[i]     = As[kk][ty * 4 + i];
                a[i + 4] = As[kk][64 + ty * 4 + i];
                b[i]     = Bs[kk][tx * 4 + i];
                b[i + 4] = Bs[kk][64 + tx * 4 + i];
            }
#pragma unroll
            for (int i = 0; i < 8; i++)
#pragma unroll
                for (int j = 0; j < 8; j++) acc[i][j] += a[i] * b[j];
        }
        __syncthreads();
    }

#pragma unroll
    for (int i = 0; i < 8; i++) {
        int r = bm + ty * 4 + (i & 3) + (i >> 2) * 64;
        if (r >= M) continue;
#pragma unroll
        for (int j = 0; j < 8; j++) {
            int cl = tx * 4 + (j & 3) + (j >> 2) * 64;  // col within tile
            out[(size_t)r * 2048 + bn + cl] = acc[i][j] + bias[wcol0 + cl];
        }
    }
}

// ============================================================================
// lstm_step: one timestep for a batch of row-dirs.
// Block (rt, hs): rows rt*64..+63, hidden units hs*16..+15 (=> 64 gate cols
// ordered [i|f|g|o] x 16 units). GEMM h_prev @ Whh^T into LDS, then gate
// epilogue reading precomputed xw, updating c and h_next.
// mode 0: sentence+heading (rows: 640 sf | 640 sb | 64 hf | 64 hb)
// mode 1: document (rows: 64 f | 64 b), also writes all-step outputs.
// ============================================================================
__global__ __launch_bounds__(256) void lstm_step(
    int mode, int t,
    const float* __restrict__ xw,       // mode0: sen xw base; mode1: doc xw
    const float* __restrict__ xw_head,  // mode0 only
    const float* __restrict__ whh_f, const float* __restrict__ whh_b,
    const float* __restrict__ h_prev, float* __restrict__ h_next,
    float* __restrict__ c,
    float* __restrict__ documents)
{
    __shared__ float Hs[16][65];
    __shared__ float Ws[16][65];
    __shared__ float Gs[64][65];
    const int tid = threadIdx.x;
    const int r0 = blockIdx.x * 64;
    const int j0 = blockIdx.y * 16;

    bool bwd;
    if (mode == 0) bwd = (r0 >= 640 && r0 < 1280) || (r0 >= 1344);
    else           bwd = (r0 >= 64);
    const float* whh = bwd ? whh_b : whh_f;

    const int lRow = tid >> 2;          // 0..63 (row for Hs, gate-col for Ws)
    const int lK0  = (tid & 3) * 4;
    const int wrow = ((lRow >> 4) * 256) + j0 + (lRow & 15);
    const float* wptr = whh + (size_t)wrow * 256;
    const float* hptr = h_prev + (size_t)(r0 + lRow) * 256;

    const int tx = tid & 15, ty = tid >> 4;
    float acc[4][4];
#pragma unroll
    for (int i = 0; i < 4; i++)
#pragma unroll
        for (int j = 0; j < 4; j++) acc[i][j] = 0.f;

    for (int k0 = 0; k0 < 256; k0 += 16) {
#pragma unroll
        for (int i = 0; i < 4; i++) {
            Hs[lK0 + i][lRow] = hptr[k0 + lK0 + i];
            Ws[lK0 + i][lRow] = wptr[k0 + lK0 + i];
        }
        __syncthreads();
#pragma unroll
        for (int kk = 0; kk < 16; kk++) {
            float a[4], b[4];
#pragma unroll
            for (int i = 0; i < 4; i++) { a[i] = Hs[kk][ty * 4 + i]; b[i] = Ws[kk][tx * 4 + i]; }
#pragma unroll
            for (int i = 0; i < 4; i++)
#pragma unroll
                for (int j = 0; j < 4; j++) acc[i][j] += a[i] * b[j];
        }
        __syncthreads();
    }
#pragma unroll
    for (int i = 0; i < 4; i++)
#pragma unroll
        for (int j = 0; j < 4; j++) Gs[ty * 4 + i][tx * 4 + j] = acc[i][j];
    __syncthreads();

    // epilogue: 4 (row, unit) pairs per thread
#pragma unroll
    for (int pp = 0; pp < 4; pp++) {
        int p = tid + pp * 256;
        int row = p >> 4;
        int u = p & 15;
        int gr = r0 + row;
        int j = j0 + u;
        const float* xwp;
        if (mode == 0) {
            if (gr < 640)       xwp = xw + (size_t)(gr * 30 + t) * 2048 + j;
            else if (gr < 1280) xwp = xw + (size_t)((gr - 640) * 30 + 29 - t) * 2048 + 1024 + j;
            else if (gr < 1344) xwp = xw_head + (size_t)((gr - 1280) * 15 + t) * 2048 + j;
            else                xwp = xw_head + (size_t)((gr - 1344) * 15 + 14 - t) * 2048 + 1024 + j;
        } else {
            if (gr < 64)        xwp = xw + (size_t)(gr * 10 + t) * 2048 + j;
            else                xwp = xw + (size_t)((gr - 64) * 10 + 9 - t) * 2048 + 1024 + j;
        }
        float gi = Gs[row][u]      + xwp[0];
        float gf = Gs[row][16 + u] + xwp[256];
        float gg = Gs[row][32 + u] + xwp[512];
        float go = Gs[row][48 + u] + xwp[768];
        float I = sigm(gi), F = sigm(gf), G = tanhf(gg), O = sigm(go);
        size_t sidx = (size_t)gr * 256 + j;
        float cn = F * c[sidx] + I * G;
        float hn = O * tanhf(cn);
        c[sidx] = cn;
        h_next[sidx] = hn;
        if (mode == 1) {
            if (gr < 64) documents[(size_t)(gr * 10 + t) * 512 + j] = hn;
            else         documents[(size_t)((gr - 64) * 10 + 9 - t) * 512 + 256 + j] = hn;
        }
    }
}

// gather final hidden states into [B*S, 512] sentences and [B, 512] headings
__global__ __launch_bounds__(256) void copy_hidden(
    const float* __restrict__ h_sen,   // buffer holding final sentence h
    const float* __restrict__ h_head,  // buffer holding final heading h
    float* __restrict__ sentences, float* __restrict__ headings)
{
    int idx = blockIdx.x * 256 + threadIdx.x;
    if (idx < 640 * 512) {
        int n = idx >> 9, j = idx & 511;
        float v = (j < 256) ? h_sen[(size_t)n * 256 + j]
                            : h_sen[(size_t)(640 + n) * 256 + (j - 256)];
        sentences[idx] = v;
    } else if (idx < 704 * 512) {
        int m = idx - 640 * 512;
        int b = m >> 9, j = m & 511;
        float v = (j < 256) ? h_head[(size_t)(1280 + b) * 256 + j]
                            : h_head[(size_t)(1344 + b) * 256 + (j - 256)];
        headings[m] = v;
    }
}

// SourceBias: biased[t] = tanh(sen[t] @ trans[u] + sb_bias[u]); block per token
__global__ __launch_bounds__(256) void source_bias(
    const float* __restrict__ sentences, const int* __restrict__ urls,
    const float* __restrict__ trans, const float* __restrict__ sb_bias,
    float* __restrict__ biased)
{
    int tkn = blockIdx.x;
    int u = urls[tkn];
    const float* Tm = trans + (size_t)u * 512 * 512;
    __shared__ float sv[512];
    for (int i = threadIdx.x; i < 512; i += 256) sv[i] = sentences[(size_t)tkn * 512 + i];
    __syncthreads();
    int e0 = threadIdx.x;
    float a0 = 0.f, a1 = 0.f;
    for (int d = 0; d < 512; d++) {
        float s = sv[d];
        a0 += s * Tm[(size_t)d * 512 + e0];
        a1 += s * Tm[(size_t)d * 512 + e0 + 256];
    }
    biased[(size_t)tkn * 512 + e0]       = tanhf(a0 + sb_bias[(size_t)u * 512 + e0]);
    biased[(size_t)tkn * 512 + e0 + 256] = tanhf(a1 + sb_bias[(size_t)u * 512 + e0 + 256]);
}

// v[b,d] = sum_e attn_W[d,e] * heading[b,e]; block per b
__global__ __launch_bounds__(256) void attn_v(
    const float* __restrict__ W, const float* __restrict__ headings,
    float* __restrict__ v)
{
    int b = blockIdx.x;
    __shared__ float hh[512];
    for (int i = threadIdx.x; i < 512; i += 256) hh[i] = headings[(size_t)b * 512 + i];
    __syncthreads();
    for (int d = threadIdx.x; d < 512; d += 256) {
        float a = 0.f;
        const float* wr = W + (size_t)d * 512;
        for (int e = 0; e < 512; e++) a += wr[e] * hh[e];
        v[(size_t)b * 512 + d] = a;
    }
}

// scores -> softmax -> doc_rep -> both MLP heads; block per batch element
__global__ __launch_bounds__(256) void attn_heads(
    const float* __restrict__ documents, const float* __restrict__ v,
    const float* __restrict__ attn_b,
    const float* __restrict__ bW1, const float* __restrict__ bb1,
    const float* __restrict__ bW2, const float* __restrict__ bb2,
    const float* __restrict__ tW1, const float* __restrict__ tb1,
    const float* __restrict__ tW2, const float* __restrict__ tb2,
    float* __restrict__ out)
{
    int b = blockIdx.x;
    int tid = threadIdx.x;
    __shared__ float vv[512];
    __shared__ float dr[512];
    __shared__ float h1s[256];
    __shared__ float t1s[256];
    __shared__ float red[256];
    __shared__ float sw[10];
    __shared__ float lg[5];
    for (int i = tid; i < 512; i += 256) vv[i] = v[(size_t)b * 512 + i];
    __syncthreads();
    for (int s = 0; s < 10; s++) {
        float p = 0.f;
        const float* dp = documents + (size_t)(b * 10 + s) * 512;
        for (int d = tid; d < 512; d += 256) p += dp[d] * vv[d];
        red[tid] = p; __syncthreads();
        for (int st = 128; st > 0; st >>= 1) {
            if (tid < st) red[tid] += red[tid + st];
            __syncthreads();
        }
        if (tid == 0) sw[s] = red[0] + attn_b[0];
        __syncthreads();
    }
    if (tid == 0) {
        float mx = sw[0];
        for (int s = 1; s < 10; s++) mx = fmaxf(mx, sw[s]);
        float sum = 0.f;
        for (int s = 0; s < 10; s++) { sw[s] = expf(sw[s] - mx); sum += sw[s]; }
        for (int s = 0; s < 10; s++) sw[s] /= sum;
    }
    __syncthreads();
    for (int d = tid; d < 512; d += 256) {
        float a = 0.f;
        for (int s = 0; s < 10; s++) a += sw[s] * documents[(size_t)(b * 10 + s) * 512 + d];
        dr[d] = a;
    }
    __syncthreads();
    {
        float a = bb1[tid], a2 = tb1[tid];
        const float* w1 = bW1 + (size_t)tid * 512;
        const float* w2 = tW1 + (size_t)tid * 512;
        for (int k = 0; k < 512; k++) { float x = dr[k]; a += x * w1[k]; a2 += x * w2[k]; }
        h1s[tid] = tanhf(a); t1s[tid] = tanhf(a2);
    }
    __syncthreads();
    if (tid < 5) {
        float a = bb2[tid];
        const float* w = bW2 + (size_t)tid * 256;
        for (int k = 0; k < 256; k++) a += h1s[k] * w[k];
        lg[tid] = tanhf(a);
    }
    if (tid == 32) {
        float a = tb2[0];
        for (int k = 0; k < 256; k++) a += t1s[k] * tW2[k];
        out[320 + b] = 1.f / (1.f + expf(-tanhf(a)));
    }
    __syncthreads();
    if (tid == 0) {
        float mx = lg[0];
        for (int j = 1; j < 5; j++) mx = fmaxf(mx, lg[j]);
        float sum = 0.f; float e[5];
        for (int j = 0; j < 5; j++) { e[j] = expf(lg[j] - mx); sum += e[j]; }
        for (int j = 0; j < 5; j++) out[b * 5 + j] = e[j] / sum;
    }
}

extern "C" void kernel_launch(void* const* d_in, const int* in_sizes, int n_in,
                              void* d_out, int out_size, void* d_ws, size_t ws_size,
                              hipStream_t stream)
{
    (void)in_sizes; (void)n_in; (void)out_size; (void)ws_size;
    const int*   input_ids = (const int*)d_in[0];
    const int*   urls      = (const int*)d_in[1];
    const int*   titles    = (const int*)d_in[2];
    const float* emb       = (const float*)d_in[3];
    const float* sen_wih_f = (const float*)d_in[4];
    const float* sen_whh_f = (const float*)d_in[5];
    const float* sen_b_f   = (const float*)d_in[6];
    const float* sen_wih_b = (const float*)d_in[7];
    const float* sen_whh_b = (const float*)d_in[8];
    const float* sen_b_b   = (const float*)d_in[9];
    const float* trans     = (const float*)d_in[10];
    const float* sb_bias   = (const float*)d_in[11];
    const float* doc_wih_f = (const float*)d_in[12];
    const float* doc_whh_f = (const float*)d_in[13];
    const float* doc_b_f   = (const float*)d_in[14];
    const float* doc_wih_b = (const float*)d_in[15];
    const float* doc_whh_b = (const float*)d_in[16];
    const float* doc_b_b   = (const float*)d_in[17];
    const float* attn_W    = (const float*)d_in[18];
    const float* attn_b    = (const float*)d_in[19];
    const float* bias_W1   = (const float*)d_in[20];
    const float* bias_b1   = (const float*)d_in[21];
    const float* bias_W2   = (const float*)d_in[22];
    const float* bias_b2   = (const float*)d_in[23];
    const float* truth_W1  = (const float*)d_in[24];
    const float* truth_b1  = (const float*)d_in[25];
    const float* truth_W2  = (const float*)d_in[26];
    const float* truth_b2  = (const float*)d_in[27];
    float* out = (float*)d_out;

    // workspace layout (f32 elements), total ~179 MB
    float* ws = (float*)d_ws;
    size_t off = 0;
    float* xw_all    = ws + off; off += (size_t)20160 * 2048;   // sen(19200)+head(960) gate projections
    float* h0        = ws + off; off += (size_t)NROWS_SEN * 256;
    float* h1        = ws + off; off += (size_t)NROWS_SEN * 256;
    float* cs        = ws + off; off += (size_t)NROWS_SEN * 256;
    float* sentences = ws + off; off += (size_t)640 * 512;
    float* headings  = ws + off; off += (size_t)64 * 512;
    float* biased    = ws + off; off += (size_t)640 * 512;
    float* xw_doc    = ws + off; off += (size_t)640 * 2048;
    float* hd0       = ws + off; off += (size_t)128 * 256;
    float* hd1       = ws + off; off += (size_t)128 * 256;
    float* cd        = ws + off; off += (size_t)128 * 256;
    float* documents = ws + off; off += (size_t)64 * 10 * 512;
    float* vbuf      = ws + off; off += (size_t)64 * 512;
    float* xw_head   = xw_all + (size_t)19200 * 2048;

    dim3 blk(256);

    // zero LSTM states (ws is poisoned before every call)
    hipMemsetAsync(h0, 0, sizeof(float) * (size_t)3 * NROWS_SEN * 256, stream);
    hipMemsetAsync(hd0, 0, sizeof(float) * (size_t)3 * 128 * 256, stream);

    // K1: gather + input projection for sentence words (19200) + title words (960)
    proj_gemm<<<dim3(158, 16), blk, 0, stream>>>(
        emb, input_ids, titles, 19200, 20160, WEMB,
        sen_wih_f, sen_wih_b, sen_b_f, sen_b_b, xw_all);

    // sentence + heading BiLSTM steps (h ping-pong: t even reads h0 writes h1)
    for (int t = 0; t < 30; t++) {
        float* hp = (t & 1) ? h1 : h0;
        float* hn = (t & 1) ? h0 : h1;
        dim3 gs(t < 15 ? 22 : 20, 16);
        lstm_step<<<gs, blk, 0, stream>>>(0, t, xw_all, xw_head,
                                          sen_whh_f, sen_whh_b, hp, hn, cs, nullptr);
    }
    // sen final h written at t=29 -> h0; head final h written at t=14 -> h1
    copy_hidden<<<dim3((704 * 512 + 255) / 256), blk, 0, stream>>>(h0, h1, sentences, headings);

    source_bias<<<dim3(640), blk, 0, stream>>>(sentences, urls, trans, sb_bias, biased);

    // doc input projection
    proj_gemm<<<dim3(5, 16), blk, 0, stream>>>(
        biased, nullptr, nullptr, 0, 640, SEN2,
        doc_wih_f, doc_wih_b, doc_b_f, doc_b_b, xw_doc);

    // doc BiLSTM steps (writes all timesteps into documents)
    for (int t = 0; t < 10; t++) {
        float* hp = (t & 1) ? hd1 : hd0;
        float* hn = (t & 1) ? hd0 : hd1;
        lstm_step<<<dim3(2, 16), blk, 0, stream>>>(1, t, xw_doc, nullptr,
                                                   doc_whh_f, doc_whh_b, hp, hn, cd, documents);
    }

    attn_v<<<dim3(64), blk, 0, stream>>>(attn_W, headings, vbuf);
    attn_heads<<<dim3(64), blk, 0, stream>>>(documents, vbuf, attn_b,
                                             bias_W1, bias_b1, bias_W2, bias_b2,
                                             truth_W1, truth_b1, truth_W2, truth_b2,
                                             out);
}